// Round 1
// baseline (977.814 us; speedup 1.0000x reference)
//
#include <hip/hip_runtime.h>
#include <cstdint>

typedef __attribute__((ext_vector_type(4))) float f32x4;
typedef __attribute__((ext_vector_type(8))) short bf16x8;
typedef __attribute__((ext_vector_type(4))) short bf16x4;

#define DEV static __device__ __forceinline__

// round-to-nearest-even f32 -> bf16 (bit pattern)
DEV unsigned short f2bf(float f) {
    union { float f; unsigned int u; } v; v.f = f;
    unsigned int u = v.u;
    return (unsigned short)((u + 0x7FFFu + ((u >> 16) & 1u)) >> 16);
}

// async global->LDS 16B per lane; LDS dest = wave-uniform base + lane*16
DEV void async_cp16(const void* g, void* l) {
    __builtin_amdgcn_global_load_lds(
        (const __attribute__((address_space(1))) unsigned int*)g,
        (__attribute__((address_space(3))) unsigned int*)l,
        16, 0, 0);
}

// ---------------------------------------------------------------------------
// Kernel 0: weight prep.
//  w1t[n][k] = bf16(w0[k]*w1[k][n])   (512 x 1024, k contiguous)
//  w2t[n][k] = bf16(w0[k]*w2[k][n])
//  w3t[j][n] = bf16(w3[n][j])         (1024 x 512, n contiguous)
// ---------------------------------------------------------------------------
__global__ void prep_w(const float* __restrict__ w0, const float* __restrict__ w1,
                       const float* __restrict__ w2, const float* __restrict__ w3,
                       unsigned short* __restrict__ w1t, unsigned short* __restrict__ w2t,
                       unsigned short* __restrict__ w3t) {
    int t = blockIdx.x * 256 + threadIdx.x;   // 0 .. 3*524288-1
    int sec = t >> 19;
    int idx = t & 524287;
    if (sec == 0) {
        int n = idx >> 10, k = idx & 1023;
        w1t[idx] = f2bf(w0[k] * w1[k * 512 + n]);
    } else if (sec == 1) {
        int n = idx >> 10, k = idx & 1023;
        w2t[idx] = f2bf(w0[k] * w2[k * 512 + n]);
    } else {
        int j = idx >> 9, n = idx & 511;
        w3t[idx] = f2bf(w3[n * 1024 + j]);
    }
}

// ---------------------------------------------------------------------------
// Kernel 1: fused RMSNorm + dual GEMM (gate/up) + SiLU-gate -> x3 (bf16, M x 512)
// Block tile 128(M) x 128(N'), BK=64, 256 threads (4 waves as 2x2 of 64x64).
// l = rsqrt(mean(x^2)) accumulated during A-staging, applied in epilogue.
// ---------------------------------------------------------------------------
__global__ __launch_bounds__(256, 2)
void ffn_gate(const float* __restrict__ x,
              const unsigned short* __restrict__ w1t,
              const unsigned short* __restrict__ w2t,
              unsigned short* __restrict__ x3) {
    __shared__ unsigned short aLds[128][72];      // +8 pad: 2-way banks (free)
    __shared__ unsigned short b1Lds[128 * 64];    // linear dest, source-swizzled
    __shared__ unsigned short b2Lds[128 * 64];
    __shared__ float part[128][16];               // per-row sumsq partials
    __shared__ float lrow[128];

    const int tid = threadIdx.x;
    const int lane = tid & 63;
    const int wv = tid >> 6;
    const int wr = wv >> 1, wc = wv & 1;
    const int lhi = lane >> 4, llo = lane & 15;

    // bijective XCD-chunked swizzle: 4 nt-sharers of an x panel land adjacent
    // on one XCD (L2 reuse of the 512KB x tile). 4096 % 8 == 0.
    int bid = blockIdx.x;
    int wgid = (bid & 7) * 512 + (bid >> 3);
    const int mt = wgid >> 2, nt = wgid & 3;
    const float* xA = x + (long)mt * 128 * 1024;
    const int n0 = nt * 128;

    for (int i = tid; i < 128 * 16; i += 256) (&part[0][0])[i] = 0.0f;

    f32x4 accg[4][4], accu[4][4];
#pragma unroll
    for (int i = 0; i < 4; ++i)
#pragma unroll
        for (int j = 0; j < 4; ++j) {
            accg[i][j] = (f32x4){0.f, 0.f, 0.f, 0.f};
            accu[i][j] = (f32x4){0.f, 0.f, 0.f, 0.f};
        }

    const int prow = tid >> 4;    // partial slot owned by this thread
    const int pcol = tid & 15;

    for (int kt = 0; kt < 16; ++kt) {
        __syncthreads();
        // ---- stage A: 128x64 f32 -> bf16, accumulate sumsq --------------
        {
            const float* xs = xA + kt * 64;
#pragma unroll
            for (int i = 0; i < 8; ++i) {
                int chunk = i * 256 + tid;          // 2048 chunks of 4 floats
                int row = chunk >> 4;
                int c4 = (chunk & 15) << 2;
                f32x4 v = *(const f32x4*)(xs + row * 1024 + c4);
                part[i * 16 + prow][pcol] += v.x * v.x + v.y * v.y + v.z * v.z + v.w * v.w;
                bf16x4 b;
                b.x = (short)f2bf(v.x); b.y = (short)f2bf(v.y);
                b.z = (short)f2bf(v.z); b.w = (short)f2bf(v.w);
                *(bf16x4*)&aLds[row][c4] = b;
            }
        }
        // ---- stage B1/B2: global_load_lds, source-swizzled --------------
#pragma unroll
        for (int i = 0; i < 4; ++i) {
            int c = i * 256 + wv * 64 + lane;       // 16B chunks
            int row = c >> 3;
            int sslot = (c & 7) ^ (row & 7);        // inverse-swizzled source
            long goff = (long)(n0 + row) * 1024 + kt * 64 + sslot * 8;
            int lbase = (i * 256 + wv * 64) * 8;    // wave-uniform, ushort units
            async_cp16(w1t + goff, b1Lds + lbase);
            async_cp16(w2t + goff, b2Lds + lbase);
        }
        __syncthreads();
        // ---- MFMA ------------------------------------------------------
#pragma unroll
        for (int kq = 0; kq < 2; ++kq) {            // k-halves of BK=64
            const int koff = kq * 32 + lhi * 8;     // A: padded linear
            const int q = kq * 4 + lhi;             // B: 16B slot index
            bf16x8 af[4], b1f[4], b2f[4];
#pragma unroll
            for (int i = 0; i < 4; ++i) {
                int r = wr * 64 + i * 16 + llo;
                af[i] = *(const bf16x8*)&aLds[r][koff];
            }
#pragma unroll
            for (int j = 0; j < 4; ++j) {
                int r = wc * 64 + j * 16 + llo;
                int off = r * 64 + ((q ^ (r & 7)) << 3);
                b1f[j] = *(const bf16x8*)(b1Lds + off);
                b2f[j] = *(const bf16x8*)(b2Lds + off);
            }
#pragma unroll
            for (int i = 0; i < 4; ++i)
#pragma unroll
                for (int j = 0; j < 4; ++j) {
                    accg[i][j] = __builtin_amdgcn_mfma_f32_16x16x32_bf16(af[i], b1f[j], accg[i][j], 0, 0, 0);
                    accu[i][j] = __builtin_amdgcn_mfma_f32_16x16x32_bf16(af[i], b2f[j], accu[i][j], 0, 0, 0);
                }
        }
    }
    __syncthreads();
    // ---- per-row RMS scale ------------------------------------------------
    if (tid < 128) {
        float s = 0.f;
#pragma unroll
        for (int c = 0; c < 16; ++c) s += part[tid][c];
        lrow[tid] = 1.0f / sqrtf(s * (1.0f / 1024.0f));
    }
    __syncthreads();
    // ---- epilogue: apply l, SiLU-gate, store bf16 -------------------------
    unsigned short* x3p = x3 + (long)mt * 128 * 512 + n0;
#pragma unroll
    for (int i = 0; i < 4; ++i) {
#pragma unroll
        for (int r = 0; r < 4; ++r) {
            int rloc = wr * 64 + i * 16 + (lhi << 2) + r;   // C/D: row=(lane>>4)*4+reg
            float l = lrow[rloc];
#pragma unroll
            for (int j = 0; j < 4; ++j) {
                float g = accg[i][j][r] * l;
                float u = accu[i][j][r] * l;
                float s = (g / (1.0f + __expf(-g))) * u;
                x3p[(long)rloc * 512 + wc * 64 + j * 16 + llo] = f2bf(s);  // col=lane&15
            }
        }
    }
}

// ---------------------------------------------------------------------------
// Kernel 2: out = x3 @ w3t  (M x 1024 fp32). 128x128 tiles, K=512, BK=64.
// ---------------------------------------------------------------------------
__global__ __launch_bounds__(256, 3)
void down_gemm(const unsigned short* __restrict__ x3,
               const unsigned short* __restrict__ w3t,
               float* __restrict__ out) {
    __shared__ unsigned short aLds[128 * 64];
    __shared__ unsigned short bLds[128 * 64];

    const int tid = threadIdx.x;
    const int lane = tid & 63;
    const int wv = tid >> 6;
    const int wr = wv >> 1, wc = wv & 1;
    const int lhi = lane >> 4, llo = lane & 15;

    int bid = blockIdx.x;
    int wgid = (bid & 7) * 1024 + (bid >> 3);    // 8192 % 8 == 0, bijective
    const int mt = wgid >> 3, nt = wgid & 7;
    const unsigned short* xa = x3 + (long)mt * 128 * 512;
    const int n0 = nt * 128;

    f32x4 acc[4][4];
#pragma unroll
    for (int i = 0; i < 4; ++i)
#pragma unroll
        for (int j = 0; j < 4; ++j) acc[i][j] = (f32x4){0.f, 0.f, 0.f, 0.f};

    for (int kt = 0; kt < 8; ++kt) {
        __syncthreads();
#pragma unroll
        for (int i = 0; i < 4; ++i) {
            int c = i * 256 + wv * 64 + lane;
            int row = c >> 3;
            int sslot = (c & 7) ^ (row & 7);
            int lbase = (i * 256 + wv * 64) * 8;
            async_cp16(xa + (long)row * 512 + kt * 64 + sslot * 8, aLds + lbase);
            async_cp16(w3t + (long)(n0 + row) * 512 + kt * 64 + sslot * 8, bLds + lbase);
        }
        __syncthreads();
#pragma unroll
        for (int kq = 0; kq < 2; ++kq) {
            const int q = kq * 4 + lhi;
            bf16x8 af[4], bf[4];
#pragma unroll
            for (int i = 0; i < 4; ++i) {
                int r = wr * 64 + i * 16 + llo;
                af[i] = *(const bf16x8*)(aLds + r * 64 + ((q ^ (r & 7)) << 3));
            }
#pragma unroll
            for (int j = 0; j < 4; ++j) {
                int r = wc * 64 + j * 16 + llo;
                bf[j] = *(const bf16x8*)(bLds + r * 64 + ((q ^ (r & 7)) << 3));
            }
#pragma unroll
            for (int i = 0; i < 4; ++i)
#pragma unroll
                for (int j = 0; j < 4; ++j)
                    acc[i][j] = __builtin_amdgcn_mfma_f32_16x16x32_bf16(af[i], bf[j], acc[i][j], 0, 0, 0);
        }
    }
    float* op = out + (long)mt * 128 * 1024 + n0;
#pragma unroll
    for (int i = 0; i < 4; ++i) {
#pragma unroll
        for (int r = 0; r < 4; ++r) {
            int rloc = wr * 64 + i * 16 + (lhi << 2) + r;
#pragma unroll
            for (int j = 0; j < 4; ++j)
                op[(long)rloc * 1024 + wc * 64 + j * 16 + llo] = acc[i][j][r];
        }
    }
}

// ---------------------------------------------------------------------------
extern "C" void kernel_launch(void* const* d_in, const int* in_sizes, int n_in,
                              void* d_out, int out_size, void* d_ws, size_t ws_size,
                              hipStream_t stream) {
    const float* x  = (const float*)d_in[0];
    const float* w0 = (const float*)d_in[1];
    const float* w1 = (const float*)d_in[2];
    const float* w2 = (const float*)d_in[3];
    const float* w3 = (const float*)d_in[4];
    float* out = (float*)d_out;

    unsigned short* w1t = (unsigned short*)d_ws;            // 512*1024 bf16 = 1MB
    unsigned short* w2t = w1t + 512 * 1024;                 // 1MB
    unsigned short* w3t = w2t + 512 * 1024;                 // 1024*512 bf16 = 1MB
    unsigned short* x3  = w3t + 1024 * 512;                 // 131072*512 bf16 = 128MB

    prep_w<<<dim3(6144), dim3(256), 0, stream>>>(w0, w1, w2, w3, w1t, w2t, w3t);
    ffn_gate<<<dim3(4096), dim3(256), 0, stream>>>(x, w1t, w2t, x3);
    down_gemm<<<dim3(8192), dim3(256), 0, stream>>>(x3, w3t, out);
}